// Round 3
// baseline (457.615 us; speedup 1.0000x reference)
//
#include <hip/hip_runtime.h>

typedef unsigned long long u64;

#define N_SP 3136          // 56*56
#define C_IN 256
#define C_OUT 256
#define BATCH 32
#define HT 8               // rows per conv block-tile

// ---------------------------------------------------------------- weight prep
// One block per output channel o (256 threads = one per input channel).
// wc = w - mean_over_Cin; pack sign bits; alpha[o] = mean|clamp(wc)| in double.
// wbits layout: [c][word][tap] so a conv wave's 9 taps are contiguous.
// Block 0 also zeroes the stats accumulators (runs before conv in stream order).
__global__ __launch_bounds__(256) void prep_weights(const float* __restrict__ w,
                                                    u64* __restrict__ wbits,
                                                    double* __restrict__ alpha,
                                                    u64* __restrict__ stats) {
    const int o = blockIdx.x;
    const int i = threadIdx.x;           // input channel
    const int lane = i & 63, wave = i >> 6;
    if (o == 0) { stats[i] = 0ull; stats[256 + i] = 0ull; }
    __shared__ double red[256];
    __shared__ double mean[9];

    float wv[9];
    const float* wp = w + ((size_t)o * C_IN + i) * 9;
#pragma unroll
    for (int t = 0; t < 9; ++t) wv[t] = wp[t];

    double asum = 0.0;
    for (int t = 0; t < 9; ++t) {
        red[i] = (double)wv[t];
        __syncthreads();
        for (int s = 128; s > 0; s >>= 1) {
            if (i < s) red[i] += red[i + s];
            __syncthreads();
        }
        if (i == 0) mean[t] = red[0] * (1.0 / 256.0);
        __syncthreads();
        double wc = (double)wv[t] - mean[t];
        u64 m = __ballot(wc > 0.0);
        if (lane == 0) wbits[((size_t)o * 4 + wave) * 9 + t] = m;
        double aw = fabs(wc);
        if (aw > 1.0) aw = 1.0;
        asum += aw;
        __syncthreads();   // before red reuse
    }
    red[i] = asum;
    __syncthreads();
    for (int s = 128; s > 0; s >>= 1) {
        if (i < s) red[i] += red[i + s];
        __syncthreads();
    }
    if (i == 0) alpha[o] = red[0] * (1.0 / 2304.0);
}

// ---------------------------------------------------------------- pack x signs
// grid (392, 4): blockIdx.y = word. For each j, 64 consecutive lanes read 64
// consecutive floats -> fully coalesced.
__global__ __launch_bounds__(256) void pack_x(const float* __restrict__ x,
                                              u64* __restrict__ xbits) {
    const int pos = blockIdx.x * 256 + threadIdx.x;    // 0 .. 100351
    const int word = blockIdx.y;                       // 0..3
    const int b = pos / N_SP;
    const int sp = pos - b * N_SP;
    const float* xp = x + ((size_t)b * C_IN + word * 64) * N_SP + sp;
    u64 m = 0;
#pragma unroll
    for (int j = 0; j < 64; ++j) {
        m |= (u64)(xp[(size_t)j * N_SP] > 0.0f) << j;
    }
    xbits[((size_t)pos << 2) + word] = m;
}

// ---------------------------------------------------------------- popcount conv
// grid (224, 256): x = spatial tile (32 b x 7 row-tiles), y = output channel.
// Block 256 = 4 waves; wave = one 64-channel word (only 9 u64 weights live per
// wave -> register-resident, no remat; R2's 1-channel-per-wave needed 36 u64
// and the compiler rematerialized the loads every row, 5x the VALU floor).
// lane = output column (56 active of 64). Per-word partial mismatch counts
// combine across waves through LDS; epilogue assigns 2 rows per wave.
__global__ __launch_bounds__(256, 4) void conv_popc(const u64* __restrict__ xbits,
                                                    const u64* __restrict__ wbits,
                                                    float* __restrict__ out,
                                                    u64* __restrict__ stats) {
    const int wave = threadIdx.x >> 6;   // word index
    const int lane = threadIdx.x & 63;
    const int tile = blockIdx.x;
    const int b = tile / 7;
    const int h0 = (tile % 7) * HT;
    const int c = blockIdx.y;
    const int w = lane;
    const bool active = (w < 56);
    const int wcl = active ? w : 55;

    __shared__ int psh[4 * HT * 64];     // [word][row][lane] partial mismatches
    __shared__ u64 sred[8];

    // 9 taps for (c, word), contiguous 72B
    u64 W[9];
    const u64* wp = wbits + ((size_t)c * 4 + wave) * 9;
#pragma unroll
    for (int t = 0; t < 9; ++t) W[t] = wp[t];

    // xbits element for position p, this word: xb[p<<2]
    const u64* xb = xbits + (((size_t)b * N_SP) << 2) + wave;
    u64 a0 = 0, a1, a2;
    a1 = xb[(size_t)(h0 * 56 + wcl) << 2];
    a2 = xb[(size_t)((h0 + 1) * 56 + wcl) << 2];
    if (h0 > 0) a0 = xb[(size_t)((h0 - 1) * 56 + wcl) << 2];

#pragma unroll
    for (int hh = 0; hh < HT; ++hh) {
        const int h = h0 + hh;
        int Q0 = 0, Q1 = 0, Q2 = 0;
        if (h > 0) {
            Q0 += __popcll(a0 ^ W[0]); Q1 += __popcll(a0 ^ W[1]); Q2 += __popcll(a0 ^ W[2]);
        }
        Q0 += __popcll(a1 ^ W[3]); Q1 += __popcll(a1 ^ W[4]); Q2 += __popcll(a1 ^ W[5]);
        if (h < 55) {
            Q0 += __popcll(a2 ^ W[6]); Q1 += __popcll(a2 ^ W[7]); Q2 += __popcll(a2 ^ W[8]);
        }
        if (!active) { Q0 = 0; Q1 = 0; Q2 = 0; }
        int L = __shfl_up(Q0, 1);
        if (lane == 0) L = 0;
        int R = __shfl_down(Q2, 1);      // lane 55 reads lane 56 (zeroed)
        psh[(wave * HT + hh) * 64 + lane] = L + Q1 + R;
        if (hh < HT - 1) {
            a0 = a1; a1 = a2;
            if (h + 2 < 56) a2 = xb[(size_t)((h + 2) * 56 + wcl) << 2];
        }
    }
    __syncthreads();

    // epilogue: each wave finalizes rows {wave*2, wave*2+1}
    int isum = 0;
    unsigned usq = 0;
    float* outc = out + ((size_t)b * C_OUT + c) * N_SP;
    const int vc = 3 - (w == 0) - (w == 55);
    if (active) {
#pragma unroll
        for (int i = 0; i < 2; ++i) {
            const int row = wave * 2 + i;
            const int h = h0 + row;
            const int nr = (h > 0) + 1 + (h < 55);
            int P = psh[(0 * HT + row) * 64 + lane]
                  + psh[(1 * HT + row) * 64 + lane]
                  + psh[(2 * HT + row) * 64 + lane]
                  + psh[(3 * HT + row) * 64 + lane];
            int S = ((nr * vc) << 8) - (P << 1);   // exact integer conv sum
            outc[h * 56 + w] = (float)S;
            isum += S;
            usq += (unsigned)(S * S);
        }
    }
    // wave reduce (|isum| per wave < 2^19, usq < 2^30)
#pragma unroll
    for (int off = 32; off > 0; off >>= 1) {
        isum += __shfl_down(isum, off);
        usq += (unsigned)__shfl_down((int)usq, off);
    }
    if (lane == 0) {
        sred[wave] = (u64)(long long)isum;
        sred[4 + wave] = (u64)usq;
    }
    __syncthreads();
    if (threadIdx.x == 0) {
        long long s1 = (long long)sred[0] + (long long)sred[1]
                     + (long long)sred[2] + (long long)sred[3];
        u64 s2 = sred[4] + sred[5] + sred[6] + sred[7];
        atomicAdd(&stats[c], (u64)s1);
        atomicAdd(&stats[C_OUT + c], s2);
    }
}

// ---------------------------------------------------------------- BN consts
__global__ void make_consts(const u64* __restrict__ stats,
                            const double* __restrict__ alpha,
                            const float* __restrict__ gamma,
                            const float* __restrict__ beta,
                            double* __restrict__ AB) {
    const int c = threadIdx.x;
    const double N = (double)(BATCH * N_SP);
    double s1 = (double)(long long)stats[c];
    double s2 = (double)(long long)stats[C_OUT + c];
    double mu = s1 / N;
    double var = s2 / N - mu * mu;
    double a = alpha[c];
    double vy = a * a * var;
    double scale = (double)gamma[c] / sqrt(vy + 1e-5);
    double A = a * scale;
    double B = (double)beta[c] - A * mu;
    AB[c] = A;
    AB[C_OUT + c] = B;
}

// ---------------------------------------------------------------- finalize
// In-place: d_out holds exact-integer S as float; out = (A*S+B > 0) ? 1 : 0.
__global__ __launch_bounds__(256) void finalize(float* __restrict__ out,
                                                const double* __restrict__ AB) {
    const unsigned i4 = blockIdx.x * 256 + threadIdx.x;   // 0 .. 6422527
    const unsigned e = i4 << 2;                            // element base
    const int c = (int)((e / N_SP) & (C_OUT - 1));         // 3136 | 4 -> c uniform in float4
    const double A = AB[c];
    const double B = AB[C_OUT + c];
    float4 v = ((float4*)out)[i4];
    v.x = (A * (double)v.x + B) > 0.0 ? 1.0f : 0.0f;
    v.y = (A * (double)v.y + B) > 0.0 ? 1.0f : 0.0f;
    v.z = (A * (double)v.z + B) > 0.0 ? 1.0f : 0.0f;
    v.w = (A * (double)v.w + B) > 0.0 ? 1.0f : 0.0f;
    ((float4*)out)[i4] = v;
}

// ---------------------------------------------------------------- launch
extern "C" void kernel_launch(void* const* d_in, const int* in_sizes, int n_in,
                              void* d_out, int out_size, void* d_ws, size_t ws_size,
                              hipStream_t stream) {
    const float* x      = (const float*)d_in[0];
    const float* weight = (const float*)d_in[1];
    const float* bias   = (const float*)d_in[2];   (void)bias;  // cancels in BN
    const float* gamma  = (const float*)d_in[3];
    const float* beta   = (const float*)d_in[4];
    float* out = (float*)d_out;

    char* ws = (char*)d_ws;
    u64*    stats = (u64*)(ws);                 // [512]
    double* alpha = (double*)(ws + 4096);       // [256]
    double* AB    = (double*)(ws + 8192);       // [512]
    u64*    wbits = (u64*)(ws + 16384);         // [256*4*9]
    u64*    xbits = (u64*)(ws + 98304);         // [32*3136*4]

    prep_weights<<<C_OUT, 256, 0, stream>>>(weight, wbits, alpha, stats);
    pack_x<<<dim3(BATCH * N_SP / 256, 4), 256, 0, stream>>>(x, xbits);
    conv_popc<<<dim3(BATCH * 7, C_OUT), 256, 0, stream>>>(xbits, wbits, out, stats);
    make_consts<<<1, C_OUT, 0, stream>>>(stats, alpha, gamma, beta, AB);
    finalize<<<(out_size / 4) / 256, 256, 0, stream>>>(out, AB);
}